// Round 1
// 260.858 us; speedup vs baseline: 1.0058x; 1.0058x over previous
//
#include <hip/hip_runtime.h>

#define NUM_BINS 128
#define BATCH 128
#define HW (512 * 512)          // elements per image
#define BLOCKS_PER_IMG 32
#define ELEMS_PER_BLOCK (HW / BLOCKS_PER_IMG)   // 8192
#define HIST_THREADS 256
#define NCOPY 32                // one histogram copy per LDS bank

// ---------------------------------------------------------------------------
// Kernel 1: per-batch histogram, torch.histc(min=0,max=1) semantics.
// 32 bank-interleaved histogram copies: lane l atomics into copy (l&31) at
// address bin*32+(l&31)  ->  bank == l&31 always  ->  zero intra-wave bank
// conflicts by construction (lanes l and l+32 share a copy: free 2-way).
// Each block writes a private partial histogram (no global atomics, no
// memset needed).
// ---------------------------------------------------------------------------
__global__ __launch_bounds__(HIST_THREADS) void hist_kernel(
    const float* __restrict__ x, unsigned int* __restrict__ part) {
    __shared__ unsigned int lhist[NUM_BINS * NCOPY];   // 16 KiB, [bin][copy]

    const int tid = threadIdx.x;
    const int cpy = tid & 31;

#pragma unroll
    for (int i = tid; i < NUM_BINS * NCOPY; i += HIST_THREADS)
        lhist[i] = 0u;
    __syncthreads();

    const int b   = blockIdx.x / BLOCKS_PER_IMG;
    const int blk = blockIdx.x % BLOCKS_PER_IMG;
    const float4* xp =
        (const float4*)(x + (size_t)b * HW + (size_t)blk * ELEMS_PER_BLOCK);
    const int n4 = ELEMS_PER_BLOCK / 4;   // 2048 float4 per block

    for (int i = tid; i < n4; i += HIST_THREADS) {
        float4 v = xp[i];
        float vals[4] = {v.x, v.y, v.z, v.w};
#pragma unroll
        for (int k = 0; k < 4; ++k) {
            float f = vals[k];
            if (f >= 0.0f && f <= 1.0f) {
                int idx = (int)(f * (float)NUM_BINS);  // trunc == floor (f>=0)
                idx = min(idx, NUM_BINS - 1);          // f==1.0 -> last bin
                atomicAdd(&lhist[idx * NCOPY + cpy], 1u);
            }
        }
    }
    __syncthreads();

    // Reduce 32 copies per bin. Rotated start ((c+bin)&31) keeps the reads
    // conflict-free: at step c, thread `bin` touches bank (c+bin)&31.
    if (tid < NUM_BINS) {
        unsigned int s = 0u;
#pragma unroll
        for (int c = 0; c < NCOPY; ++c)
            s += lhist[tid * NCOPY + ((c + tid) & 31)];
        part[((size_t)b * BLOCKS_PER_IMG + blk) * NUM_BINS + tid] = s;
    }
}

// ---------------------------------------------------------------------------
// Kernel 2: sum partials + tiny MLP  w[b] = relu(hist @ W1 + b1) @ W2 + b2.
// One 128-thread block per batch. Partial sum loads are coalesced
// (consecutive threads -> consecutive bins).
// ---------------------------------------------------------------------------
__global__ __launch_bounds__(128) void mlp_kernel(
    const unsigned int* __restrict__ part,
    const float* __restrict__ W1, const float* __restrict__ b1,
    const float* __restrict__ W2, const float* __restrict__ b2,
    float* __restrict__ w) {
    __shared__ float shist[NUM_BINS];
    __shared__ float hred[16];

    const int b = blockIdx.x;
    const int t = threadIdx.x;

    unsigned int s = 0u;
    const unsigned int* p = part + (size_t)b * BLOCKS_PER_IMG * NUM_BINS + t;
#pragma unroll
    for (int blk = 0; blk < BLOCKS_PER_IMG; ++blk)
        s += p[blk * NUM_BINS];
    shist[t] = (float)s;
    __syncthreads();

    if (t < 16) {
        float acc = b1[t];
#pragma unroll 8
        for (int k = 0; k < NUM_BINS; ++k)
            acc = fmaf(shist[k], W1[k * 16 + t], acc);
        hred[t] = fmaxf(acc, 0.0f) * W2[t];   // W2 is [16,1]
    }
    __syncthreads();

    if (t == 0) {
        float sum = b2[0];
#pragma unroll
        for (int i = 0; i < 16; ++i) sum += hred[i];
        w[b] = sum;
    }
}

// ---------------------------------------------------------------------------
// Kernel 3: out = x * w[batch], vectorized float4 grid-stride.
// ---------------------------------------------------------------------------
__global__ __launch_bounds__(256) void scale_kernel(
    const float* __restrict__ x, const float* __restrict__ w,
    float* __restrict__ out) {
    const size_t total4 = (size_t)BATCH * HW / 4;   // 8,388,608
    const size_t stride = (size_t)gridDim.x * blockDim.x;
    for (size_t i = (size_t)blockIdx.x * blockDim.x + threadIdx.x; i < total4;
         i += stride) {
        int b = (int)(i >> 16);   // HW/4 = 65536 float4 per image
        float s = w[b];
        float4 v = ((const float4*)x)[i];
        v.x *= s; v.y *= s; v.z *= s; v.w *= s;
        ((float4*)out)[i] = v;
    }
}

extern "C" void kernel_launch(void* const* d_in, const int* in_sizes, int n_in,
                              void* d_out, int out_size, void* d_ws, size_t ws_size,
                              hipStream_t stream) {
    const float* x  = (const float*)d_in[0];
    const float* W1 = (const float*)d_in[1];
    const float* b1 = (const float*)d_in[2];
    const float* W2 = (const float*)d_in[3];
    const float* b2 = (const float*)d_in[4];
    float* out = (float*)d_out;

    // workspace: per-block partial histograms (128*32*128 u32 = 2 MiB) + w
    unsigned int* part = (unsigned int*)d_ws;
    float* w = (float*)((char*)d_ws +
                        (size_t)BATCH * BLOCKS_PER_IMG * NUM_BINS * sizeof(unsigned int));

    hist_kernel<<<BATCH * BLOCKS_PER_IMG, HIST_THREADS, 0, stream>>>(x, part);
    mlp_kernel<<<BATCH, 128, 0, stream>>>(part, W1, b1, W2, b2, w);

    const int total4 = BATCH * HW / 4;
    int blocks = min((total4 + 255) / 256, 16384);
    scale_kernel<<<blocks, 256, 0, stream>>>(x, w, out);
}